// Round 4
// baseline (281.289 us; speedup 1.0000x reference)
//
#include <hip/hip_runtime.h>

#define N_SAMP 48
#define RPC    16                      // rays per chunk
#define BLOCK  256
#define TPR    16                      // threads per ray (compute phase)
#define SPT    3                       // samples per thread

#define RGB_F4   (RPC * 36)            // 576 float4 per chunk
#define SIG_F4   (RPC * 12)            // 192
#define Z_F4     (RPC * 12)            // 192
#define SIG_OFF  (RPC * 144)           // float offset 2304
#define Z_OFF    (SIG_OFF + RPC * 48)  // 3072
#define LDS_FLOATS (Z_OFF + RPC * 48)  // 3840 floats = 15360 B -> 8 blocks/CU

// Chunked streaming: 16-ray tiles staged with block-linear coalesced float4
// loads into a 15 KB LDS buffer (100% occupancy: 8 blocks/CU), computed by
// 16 threads/ray (3 samples each) with a 16-lane shuffle scan for the
// exclusive transmittance product. Latency hiding comes from 8 resident
// blocks per CU alternating between load-wait and compute phases.
__global__ __launch_bounds__(BLOCK, 8) void volrender_kernel(
    const float4* __restrict__ rgb4,    // n_rays * 36 float4
    const float4* __restrict__ sigma4,  // n_rays * 12 float4
    const float4* __restrict__ z4,      // n_rays * 12 float4
    float* __restrict__ out_rgb,        // n_rays * 3 floats
    float* __restrict__ out_depth,      // n_rays floats
    int n_rays, int n_chunks)
{
    __shared__ float bf[LDS_FLOATS];
    float4* bf4 = reinterpret_cast<float4*>(bf);

    const int t   = threadIdx.x;
    const int rl  = t >> 4;            // ray within chunk
    const int sub = t & 15;            // 1/16th of the ray

    const size_t rgb_tot = (size_t)n_rays * 36;
    const size_t sz_tot  = (size_t)n_rays * 12;

    for (int chunk = blockIdx.x; chunk < n_chunks; chunk += gridDim.x) {
        const size_t ray0 = (size_t)chunk * RPC;

        if (chunk != blockIdx.x) __syncthreads();   // prev compute done before overwrite

        // ---- stage: block-linear coalesced float4 copy (5 loads/thread) ----
        {
            const size_t rb = ray0 * 36;
            const size_t zb = ray0 * 12;
            float4 a0 = make_float4(0, 0, 0, 0), a1 = a0, a2 = a0, sg = a0, zv = a0;
            if (rb + t       < rgb_tot) a0 = rgb4[rb + t];
            if (rb + 256 + t < rgb_tot) a1 = rgb4[rb + 256 + t];
            if (t < RGB_F4 - 512 && rb + 512 + t < rgb_tot) a2 = rgb4[rb + 512 + t];
            if (t < SIG_F4 && zb + t < sz_tot) sg = sigma4[zb + t];
            if (t < Z_F4   && zb + t < sz_tot) zv = z4[zb + t];
            bf4[t]       = a0;
            bf4[256 + t] = a1;
            if (t < RGB_F4 - 512) bf4[512 + t] = a2;
            if (t < SIG_F4) bf4[SIG_OFF / 4 + t] = sg;
            if (t < Z_F4)   bf4[Z_OFF / 4 + t]   = zv;
        }
        __syncthreads();

        // ---- compute: 16 threads per ray, 3 consecutive samples each ----
        const int zbase = Z_OFF + rl * 48 + sub * 3;
        const float zl0 = bf[zbase + 0];
        const float zl1 = bf[zbase + 1];
        const float zl2 = bf[zbase + 2];
        const float z3  = (sub == 15) ? 0.0f : bf[zbase + 3];  // next seg's first z

        const int sbase = SIG_OFF + rl * 48 + sub * 3;
        const float s0 = bf[sbase + 0];
        const float s1 = bf[sbase + 1];
        const float s2 = bf[sbase + 2];

        const int rbase = rl * 144 + sub * 9;
        float r[9];
#pragma unroll
        for (int k = 0; k < 9; ++k) r[k] = bf[rbase + k];

        float T = 1.0f, ar = 0.0f, ag = 0.0f, ab = 0.0f, ad = 0.0f;
        {   // sample 0
            float alpha = 1.0f - __expf(-s0 * (zl1 - zl0));
            float w = alpha * T; T *= (1.0f - alpha + 1e-10f);
            ar = fmaf(w, r[0], ar); ag = fmaf(w, r[1], ag);
            ab = fmaf(w, r[2], ab); ad = fmaf(w, zl0, ad);
        }
        {   // sample 1
            float alpha = 1.0f - __expf(-s1 * (zl2 - zl1));
            float w = alpha * T; T *= (1.0f - alpha + 1e-10f);
            ar = fmaf(w, r[3], ar); ag = fmaf(w, r[4], ag);
            ab = fmaf(w, r[5], ab); ad = fmaf(w, zl1, ad);
        }
        {   // sample 2 (last of segment; last of ray if sub==15)
            float dist  = (sub == 15) ? 1e10f : (z3 - zl2);
            float alpha = 1.0f - __expf(-s2 * dist);
            float w = alpha * T; T *= (1.0f - alpha + 1e-10f);
            ar = fmaf(w, r[6], ar); ag = fmaf(w, r[7], ag);
            ab = fmaf(w, r[8], ab); ad = fmaf(w, zl2, ad);
        }

        // ---- exclusive prefix product of segment transmittance (16 lanes) ----
        float x = T;
#pragma unroll
        for (int d = 1; d < 16; d <<= 1) {
            float v = __shfl_up(x, (unsigned)d, 16);
            if (sub >= d) x *= v;
        }
        float e = __shfl_up(x, 1u, 16);
        if (sub == 0) e = 1.0f;
        ar *= e; ag *= e; ab *= e; ad *= e;

        // ---- reduce the 16 lanes of each ray ----
#pragma unroll
        for (int d = 1; d < 16; d <<= 1) {
            ar += __shfl_xor(ar, d);
            ag += __shfl_xor(ag, d);
            ab += __shfl_xor(ab, d);
            ad += __shfl_xor(ad, d);
        }

        if (sub == 0) {
            const size_t ray = ray0 + rl;
            if (ray < (size_t)n_rays) {
                out_rgb[ray * 3 + 0] = ar;
                out_rgb[ray * 3 + 1] = ag;
                out_rgb[ray * 3 + 2] = ab;
                out_depth[ray] = ad;
            }
        }
    }
}

extern "C" void kernel_launch(void* const* d_in, const int* in_sizes, int n_in,
                              void* d_out, int out_size, void* d_ws, size_t ws_size,
                              hipStream_t stream) {
    const float4* rgb4   = (const float4*)d_in[0];  // (B,HW,48,3) f32
    const float4* sigma4 = (const float4*)d_in[1];  // (B,HW,48,1) f32
    const float4* z4     = (const float4*)d_in[2];  // (B,HW,48)   f32

    const int n_rays   = in_sizes[2] / N_SAMP;
    const int n_chunks = (n_rays + RPC - 1) / RPC;

    float* out_rgb   = (float*)d_out;
    float* out_depth = out_rgb + (size_t)n_rays * 3;

    int grid = 2048;                       // 8 blocks/CU x 256 CUs resident
    if (grid > n_chunks) grid = n_chunks;
    hipLaunchKernelGGL(volrender_kernel, dim3(grid), dim3(BLOCK), 0, stream,
                       rgb4, sigma4, z4, out_rgb, out_depth, n_rays, n_chunks);
}